// Round 1
// baseline (598.568 us; speedup 1.0000x reference)
//
#include <hip/hip_runtime.h>
#include <hip/hip_bf16.h>

// MHA for B=4, S=2048, D=1024, H=16, Dh=64.
// Pipeline: 3x GEMM (enc->Q,K,V bf16, bias fused) -> flash attention (bf16 MFMA,
// fp32 online softmax) -> GEMM (AO bf16 @ Wo^T + bo -> fp32 out).
// Workspace: Q,K,V,AO bf16 = 4 * 16.78 MB = 67.1 MB required.

#define SS 2048
#define DD 1024

typedef __attribute__((ext_vector_type(8))) short short8;
typedef __attribute__((ext_vector_type(8))) __bf16 bfv8;
typedef __attribute__((ext_vector_type(4))) float f32x4;

__device__ __forceinline__ unsigned short f2bf(float x) {
  unsigned u = __builtin_bit_cast(unsigned, x);
  u += 0x7fffu + ((u >> 16) & 1u);   // RNE
  return (unsigned short)(u >> 16);
}

// MFMA signature hedge: ROCm builds differ on whether
// __builtin_amdgcn_mfma_f32_16x16x32_bf16 takes <8 x i16> or <8 x bfloat>.
template <typename V>
__device__ __forceinline__ auto mfma_sel(V a, V b, f32x4 c, int)
    -> decltype(__builtin_amdgcn_mfma_f32_16x16x32_bf16(a, b, c, 0, 0, 0)) {
  return __builtin_amdgcn_mfma_f32_16x16x32_bf16(a, b, c, 0, 0, 0);
}
template <typename V>
__device__ __forceinline__ f32x4 mfma_sel(V a, V b, f32x4 c, long) {
  return __builtin_amdgcn_mfma_f32_16x16x32_bf16(
      __builtin_bit_cast(bfv8, a), __builtin_bit_cast(bfv8, b), c, 0, 0, 0);
}
__device__ __forceinline__ f32x4 MFMA(short8 a, short8 b, f32x4 c) {
  return mfma_sel(a, b, c, 0);
}

// C[M,1024] = A[M,1024] . W[1024,1024]^T + bias   (torch Linear semantics)
// A is fp32 (A_BF16=0) or bf16 (A_BF16=1); W/bias always fp32; C bf16 or fp32.
// 128x128 tile, BK=32, 4 waves each computing a 64x64 quadrant as 4x4 MFMA frags.
template <int A_BF16, int OUT_BF16>
__global__ __launch_bounds__(256) void gemm_bt(const void* __restrict__ Ain,
                                               const float* __restrict__ Wf,
                                               const float* __restrict__ bias,
                                               void* __restrict__ Cout) {
  __shared__ unsigned short As[128 * 32];
  __shared__ unsigned short Bs[128 * 32];
  const int t = threadIdx.x;
  const int lane = t & 63;
  const int w = t >> 6;
  const int l15 = lane & 15, g = lane >> 4;
  const int wr = w >> 1, wc = w & 1;
  const size_t m0 = (size_t)blockIdx.y * 128;
  const int n0 = blockIdx.x * 128;

  f32x4 acc[4][4];
#pragma unroll
  for (int i = 0; i < 4; i++)
#pragma unroll
    for (int j = 0; j < 4; j++) acc[i][j] = {0.f, 0.f, 0.f, 0.f};

  for (int k0 = 0; k0 < DD; k0 += 32) {
    if (A_BF16) {
      const unsigned short* A = (const unsigned short*)Ain;
#pragma unroll
      for (int i = 0; i < 2; i++) {
        int idx = t + i * 256;               // 512 chunks of 8 bf16
        int row = idx >> 2, c8 = idx & 3;
        *(short8*)(As + row * 32 + c8 * 8) =
            *(const short8*)(A + (m0 + row) * DD + k0 + c8 * 8);
      }
    } else {
      const float* A = (const float*)Ain;
#pragma unroll
      for (int i = 0; i < 4; i++) {
        int idx = t + i * 256;               // 1024 chunks of 4 floats
        int row = idx >> 3, c4 = idx & 7;
        float4 v = *(const float4*)(A + (m0 + row) * DD + k0 + c4 * 4);
        ushort4 o = {f2bf(v.x), f2bf(v.y), f2bf(v.z), f2bf(v.w)};
        *(ushort4*)(As + row * 32 + c4 * 4) = o;
      }
    }
#pragma unroll
    for (int i = 0; i < 4; i++) {
      int idx = t + i * 256;
      int row = idx >> 3, c4 = idx & 7;
      float4 v = *(const float4*)(Wf + (size_t)(n0 + row) * DD + k0 + c4 * 4);
      ushort4 o = {f2bf(v.x), f2bf(v.y), f2bf(v.z), f2bf(v.w)};
      *(ushort4*)(Bs + row * 32 + c4 * 4) = o;
    }
    __syncthreads();
    short8 af[4], bfr[4];
#pragma unroll
    for (int mi = 0; mi < 4; mi++)
      af[mi] = *(const short8*)(As + (wr * 64 + mi * 16 + l15) * 32 + g * 8);
#pragma unroll
    for (int ni = 0; ni < 4; ni++)
      bfr[ni] = *(const short8*)(Bs + (wc * 64 + ni * 16 + l15) * 32 + g * 8);
#pragma unroll
    for (int mi = 0; mi < 4; mi++)
#pragma unroll
      for (int ni = 0; ni < 4; ni++)
        acc[mi][ni] = MFMA(af[mi], bfr[ni], acc[mi][ni]);
    __syncthreads();
  }

  float bs[4];
#pragma unroll
  for (int ni = 0; ni < 4; ni++) bs[ni] = bias[n0 + wc * 64 + ni * 16 + l15];
#pragma unroll
  for (int mi = 0; mi < 4; mi++) {
#pragma unroll
    for (int ni = 0; ni < 4; ni++) {
      size_t row = m0 + wr * 64 + mi * 16 + g * 4;
      int col = n0 + wc * 64 + ni * 16 + l15;
#pragma unroll
      for (int j = 0; j < 4; j++) {
        float v = acc[mi][ni][j] + bs[ni];
        if (OUT_BF16)
          ((unsigned short*)Cout)[(row + j) * DD + col] = f2bf(v);
        else
          ((float*)Cout)[(row + j) * DD + col] = v;
      }
    }
  }
}

// Flash attention. Grid: (S/64, B*H). Block: 256 = 4 waves, each wave owns 16
// q-rows. KV tiles of 64 staged in LDS (K linear rows, V transposed), stride 80
// elems (160B: 16B-aligned ds_read_b128, ~4-way bank conflict accepted).
// scores = QK^T / 64, mask (qpad|kpad) -> -1e8, online softmax, O = P.V / l.
__global__ __launch_bounds__(256) void attn_kernel(
    const unsigned short* __restrict__ Qb, const unsigned short* __restrict__ Kb,
    const unsigned short* __restrict__ Vb, const int* __restrict__ padMask,
    unsigned short* __restrict__ AO) {
  __shared__ unsigned short Ks[64 * 80];
  __shared__ unsigned short Vt[64 * 80];
  __shared__ unsigned short Ps[4 * 16 * 80];

  const int t = threadIdx.x;
  const int w = t >> 6, lane = t & 63;
  const int l15 = lane & 15, g = lane >> 4;
  const int bh = blockIdx.y;
  const int b = bh >> 4, h = bh & 15;
  const int q0 = blockIdx.x * 64 + w * 16;
  const size_t baseBS = (size_t)b * SS;

  short8 aQ[2];
  {
    const unsigned short* qp = Qb + (baseBS + q0 + l15) * DD + h * 64 + g * 8;
    aQ[0] = *(const short8*)(qp);
    aQ[1] = *(const short8*)(qp + 32);
  }
  int qm[4];
#pragma unroll
  for (int j = 0; j < 4; j++) qm[j] = padMask[baseBS + q0 + g * 4 + j];

  float m_r[4], l_r[4];
  f32x4 acc[4];
#pragma unroll
  for (int j = 0; j < 4; j++) { m_r[j] = -1e30f; l_r[j] = 0.f; }
#pragma unroll
  for (int nb = 0; nb < 4; nb++) acc[nb] = {0.f, 0.f, 0.f, 0.f};

  unsigned short* Pw = Ps + w * 16 * 80;

  for (int kt = 0; kt < SS / 64; ++kt) {
    const int kbase = kt * 64;
#pragma unroll
    for (int i = 0; i < 2; i++) {
      int idx = t + i * 256;                 // 512 chunks of 8 bf16
      int key = idx >> 3, dc = idx & 7;
      const size_t gofs = (baseBS + kbase + key) * DD + h * 64 + dc * 8;
      *(short8*)(Ks + key * 80 + dc * 8) = *(const short8*)(Kb + gofs);
      short8 vv = *(const short8*)(Vb + gofs);
#pragma unroll
      for (int e = 0; e < 8; e++) Vt[(dc * 8 + e) * 80 + key] = (unsigned short)vv[e];
    }
    __syncthreads();

    // QK^T for this wave's 16 rows x 64 keys
    f32x4 sc[4];
#pragma unroll
    for (int kb = 0; kb < 4; kb++) {
      f32x4 s = {0.f, 0.f, 0.f, 0.f};
#pragma unroll
      for (int kk = 0; kk < 2; kk++) {
        short8 bk = *(const short8*)(Ks + (kb * 16 + l15) * 80 + kk * 32 + g * 8);
        s = MFMA(aQ[kk], bk, s);
      }
      sc[kb] = s;
    }

    int km[4];
#pragma unroll
    for (int kb = 0; kb < 4; kb++) km[kb] = padMask[baseBS + kbase + kb * 16 + l15];

    float es[4];
#pragma unroll
    for (int j = 0; j < 4; j++) {
      float rm = -3e38f;
#pragma unroll
      for (int kb = 0; kb < 4; kb++) {
        float sv = (qm[j] | km[kb]) ? -1e8f : sc[kb][j] * 0.015625f;
        sc[kb][j] = sv;
        rm = fmaxf(rm, sv);
      }
      rm = fmaxf(rm, __shfl_xor(rm, 1));
      rm = fmaxf(rm, __shfl_xor(rm, 2));
      rm = fmaxf(rm, __shfl_xor(rm, 4));
      rm = fmaxf(rm, __shfl_xor(rm, 8));
      float mnew = fmaxf(m_r[j], rm);
      es[j] = __expf(m_r[j] - mnew);
      float sum = 0.f;
#pragma unroll
      for (int kb = 0; kb < 4; kb++) {
        float pv = __expf(sc[kb][j] - mnew);
        sc[kb][j] = pv;
        sum += pv;
      }
      sum += __shfl_xor(sum, 1);
      sum += __shfl_xor(sum, 2);
      sum += __shfl_xor(sum, 4);
      sum += __shfl_xor(sum, 8);
      l_r[j] = l_r[j] * es[j] + sum;
      m_r[j] = mnew;
    }
#pragma unroll
    for (int nb = 0; nb < 4; nb++)
#pragma unroll
      for (int j = 0; j < 4; j++) acc[nb][j] *= es[j];

    // P (C-layout) -> LDS [row][key] so it can be re-read as MFMA A-frags
#pragma unroll
    for (int kb = 0; kb < 4; kb++)
#pragma unroll
      for (int j = 0; j < 4; j++)
        Pw[(g * 4 + j) * 80 + kb * 16 + l15] = f2bf(sc[kb][j]);

    short8 pa[2];
    pa[0] = *(const short8*)(Pw + l15 * 80 + g * 8);
    pa[1] = *(const short8*)(Pw + l15 * 80 + 32 + g * 8);
#pragma unroll
    for (int nb = 0; nb < 4; nb++) {
#pragma unroll
      for (int kk = 0; kk < 2; kk++) {
        short8 vb_ = *(const short8*)(Vt + (nb * 16 + l15) * 80 + kk * 32 + g * 8);
        acc[nb] = MFMA(pa[kk], vb_, acc[nb]);
      }
    }
    __syncthreads();
  }

#pragma unroll
  for (int nb = 0; nb < 4; nb++) {
#pragma unroll
    for (int j = 0; j < 4; j++) {
      float ov = acc[nb][j] / l_r[j];
      AO[(baseBS + q0 + g * 4 + j) * DD + h * 64 + nb * 16 + l15] = f2bf(ov);
    }
  }
}

extern "C" void kernel_launch(void* const* d_in, const int* in_sizes, int n_in,
                              void* d_out, int out_size, void* d_ws, size_t ws_size,
                              hipStream_t stream) {
  const float* enc = (const float*)d_in[0];
  const int* padMask = (const int*)d_in[1];
  const float* Wq = (const float*)d_in[2];
  const float* bq = (const float*)d_in[3];
  const float* Wk = (const float*)d_in[4];
  const float* bk = (const float*)d_in[5];
  const float* Wv = (const float*)d_in[6];
  const float* bv = (const float*)d_in[7];
  const float* Wo = (const float*)d_in[8];
  const float* bo = (const float*)d_in[9];
  float* out = (float*)d_out;

  const size_t NTOK = (size_t)4 * SS;      // 8192 rows
  unsigned short* Qb = (unsigned short*)d_ws;
  unsigned short* Kb = Qb + NTOK * DD;
  unsigned short* Vb = Kb + NTOK * DD;
  unsigned short* AO = Vb + NTOK * DD;

  dim3 blk(256);
  dim3 gGemm(DD / 128, NTOK / 128);        // (8, 64)
  gemm_bt<0, 1><<<gGemm, blk, 0, stream>>>((const void*)enc, Wq, bq, (void*)Qb);
  gemm_bt<0, 1><<<gGemm, blk, 0, stream>>>((const void*)enc, Wk, bk, (void*)Kb);
  gemm_bt<0, 1><<<gGemm, blk, 0, stream>>>((const void*)enc, Wv, bv, (void*)Vb);

  dim3 gAttn(SS / 64, 4 * 16);             // (32, 64)
  attn_kernel<<<gAttn, blk, 0, stream>>>(Qb, Kb, Vb, padMask, AO);

  gemm_bt<1, 0><<<gGemm, blk, 0, stream>>>((const void*)AO, Wo, bo, (void*)out);
}

// Round 5
// 408.633 us; speedup vs baseline: 1.4648x; 1.4648x over previous
//
#include <hip/hip_runtime.h>
#include <hip/hip_bf16.h>

// MHA for B=4, S=2048, D=1024, H=16, Dh=64.
// Pipeline: cvt fp32->bf16 (enc, 4x W) -> 3x bf16 GEMM (Q,K,V) -> V transpose
// -> flash attention (swapped QK^T, in-register softmax+P, XOR-swizzled LDS)
// -> GEMM (AO@Wo^T+bo -> fp32 out).
// ws extended: Qb,Kb,Vb,Vt + Ebf + 4xWbf = 92.3 MB; falls back to fp32-W GEMMs
// (67.1 MB layout) if ws_size is smaller. AO aliases Vb.

#define SS 2048
#define DD 1024

typedef __attribute__((ext_vector_type(8))) short short8;
typedef __attribute__((ext_vector_type(8))) __bf16 bfv8;
typedef __attribute__((ext_vector_type(4))) float f32x4;
typedef __attribute__((ext_vector_type(4))) unsigned u32x4;

__device__ __forceinline__ unsigned short f2bf(float x) {
  unsigned u = __builtin_bit_cast(unsigned, x);
  u += 0x7fffu + ((u >> 16) & 1u);   // RNE
  return (unsigned short)(u >> 16);
}

__device__ __forceinline__ unsigned cvtpk_bf16(float lo, float hi) {
  unsigned r;
  asm("v_cvt_pk_bf16_f32 %0, %1, %2" : "=v"(r) : "v"(lo), "v"(hi));
  return r;
}

// MFMA signature hedge (<8 x i16> vs <8 x bfloat> builds)
template <typename V>
__device__ __forceinline__ auto mfma_sel(V a, V b, f32x4 c, int)
    -> decltype(__builtin_amdgcn_mfma_f32_16x16x32_bf16(a, b, c, 0, 0, 0)) {
  return __builtin_amdgcn_mfma_f32_16x16x32_bf16(a, b, c, 0, 0, 0);
}
template <typename V>
__device__ __forceinline__ f32x4 mfma_sel(V a, V b, f32x4 c, long) {
  return __builtin_amdgcn_mfma_f32_16x16x32_bf16(
      __builtin_bit_cast(bfv8, a), __builtin_bit_cast(bfv8, b), c, 0, 0, 0);
}
__device__ __forceinline__ f32x4 MFMA(short8 a, short8 b, f32x4 c) {
  return mfma_sel(a, b, c, 0);
}

// ---------------- fp32 -> bf16 bulk convert (8 elems/thread) ----------------
__global__ __launch_bounds__(256) void cvt_f32_bf16(
    const float* __restrict__ src, unsigned short* __restrict__ dst, int n8) {
  int i = blockIdx.x * blockDim.x + threadIdx.x;
  if (i < n8) {
    float4 a = ((const float4*)src)[2 * i];
    float4 b = ((const float4*)src)[2 * i + 1];
    short8 o;
    o[0] = f2bf(a.x); o[1] = f2bf(a.y); o[2] = f2bf(a.z); o[3] = f2bf(a.w);
    o[4] = f2bf(b.x); o[5] = f2bf(b.y); o[6] = f2bf(b.z); o[7] = f2bf(b.w);
    ((short8*)dst)[i] = o;
  }
}

// ---------------- GEMM: C[M,1024] = A . W^T + bias (torch Linear) -----------
// 128x128 tile, BK=32, 4 waves x (4x4) 16x16x32 MFMA frags.
template <int A_BF16, int W_BF16, int OUT_BF16>
__global__ __launch_bounds__(256) void gemm_bt(const void* __restrict__ Ain,
                                               const void* __restrict__ Win,
                                               const float* __restrict__ bias,
                                               void* __restrict__ Cout) {
  __shared__ unsigned short As[128 * 32];
  __shared__ unsigned short Bs[128 * 32];
  const int t = threadIdx.x;
  const int lane = t & 63;
  const int w = t >> 6;
  const int l15 = lane & 15, g = lane >> 4;
  const int wr = w >> 1, wc = w & 1;
  const size_t m0 = (size_t)blockIdx.y * 128;
  const int n0 = blockIdx.x * 128;

  f32x4 acc[4][4];
#pragma unroll
  for (int i = 0; i < 4; i++)
#pragma unroll
    for (int j = 0; j < 4; j++) acc[i][j] = {0.f, 0.f, 0.f, 0.f};

  for (int k0 = 0; k0 < DD; k0 += 32) {
    if (A_BF16) {
      const unsigned short* A = (const unsigned short*)Ain;
#pragma unroll
      for (int i = 0; i < 2; i++) {
        int idx = t + i * 256;               // 512 chunks of 8 bf16
        int row = idx >> 2, c8 = idx & 3;
        *(short8*)(As + row * 32 + c8 * 8) =
            *(const short8*)(A + (m0 + row) * DD + k0 + c8 * 8);
      }
    } else {
      const float* A = (const float*)Ain;
#pragma unroll
      for (int i = 0; i < 4; i++) {
        int idx = t + i * 256;               // 1024 chunks of 4 floats
        int row = idx >> 3, c4 = idx & 7;
        float4 v = *(const float4*)(A + (m0 + row) * DD + k0 + c4 * 4);
        ushort4 o = {f2bf(v.x), f2bf(v.y), f2bf(v.z), f2bf(v.w)};
        *(ushort4*)(As + row * 32 + c4 * 4) = o;
      }
    }
    if (W_BF16) {
      const unsigned short* Wb = (const unsigned short*)Win;
#pragma unroll
      for (int i = 0; i < 2; i++) {
        int idx = t + i * 256;
        int row = idx >> 2, c8 = idx & 3;
        *(short8*)(Bs + row * 32 + c8 * 8) =
            *(const short8*)(Wb + (size_t)(n0 + row) * DD + k0 + c8 * 8);
      }
    } else {
      const float* Wf = (const float*)Win;
#pragma unroll
      for (int i = 0; i < 4; i++) {
        int idx = t + i * 256;
        int row = idx >> 3, c4 = idx & 7;
        float4 v = *(const float4*)(Wf + (size_t)(n0 + row) * DD + k0 + c4 * 4);
        ushort4 o = {f2bf(v.x), f2bf(v.y), f2bf(v.z), f2bf(v.w)};
        *(ushort4*)(Bs + row * 32 + c4 * 4) = o;
      }
    }
    __syncthreads();
    short8 af[4], bfr[4];
#pragma unroll
    for (int mi = 0; mi < 4; mi++)
      af[mi] = *(const short8*)(As + (wr * 64 + mi * 16 + l15) * 32 + g * 8);
#pragma unroll
    for (int ni = 0; ni < 4; ni++)
      bfr[ni] = *(const short8*)(Bs + (wc * 64 + ni * 16 + l15) * 32 + g * 8);
#pragma unroll
    for (int mi = 0; mi < 4; mi++)
#pragma unroll
      for (int ni = 0; ni < 4; ni++)
        acc[mi][ni] = MFMA(af[mi], bfr[ni], acc[mi][ni]);
    __syncthreads();
  }

  float bs[4];
#pragma unroll
  for (int ni = 0; ni < 4; ni++) bs[ni] = bias[n0 + wc * 64 + ni * 16 + l15];
#pragma unroll
  for (int mi = 0; mi < 4; mi++) {
#pragma unroll
    for (int ni = 0; ni < 4; ni++) {
      size_t row = m0 + wr * 64 + mi * 16 + g * 4;
      int col = n0 + wc * 64 + ni * 16 + l15;
#pragma unroll
      for (int j = 0; j < 4; j++) {
        float v = acc[mi][ni][j] + bs[ni];
        if (OUT_BF16)
          ((unsigned short*)Cout)[(row + j) * DD + col] = f2bf(v);
        else
          ((float*)Cout)[(row + j) * DD + col] = v;
      }
    }
  }
}

// ---------------- V transpose: Vb[b*S+s][h*64+d] -> Vt[(bh*64+d)][s] --------
__global__ __launch_bounds__(256) void transpose_v(
    const unsigned short* __restrict__ Vb, unsigned short* __restrict__ Vt) {
  __shared__ unsigned short L[64 * 72];   // stride 72 elems: 16B-aligned rows
  const int t = threadIdx.x;
  const int s0 = blockIdx.x * 64;
  const int bh = blockIdx.y;
  const int b = bh >> 4, h = bh & 15;
#pragma unroll
  for (int i = 0; i < 2; i++) {
    int idx = t + i * 256;
    int s = idx >> 3, dc = idx & 7;
    *(short8*)(L + s * 72 + dc * 8) =
        *(const short8*)(Vb + ((size_t)b * SS + s0 + s) * DD + h * 64 + dc * 8);
  }
  __syncthreads();
#pragma unroll
  for (int i = 0; i < 2; i++) {
    int idx = t + i * 256;
    int d = idx >> 3, sc = idx & 7;
    short8 o;
#pragma unroll
    for (int e = 0; e < 8; e++) o[e] = (short)L[(sc * 8 + e) * 72 + d];
    *(short8*)(Vt + ((size_t)bh * 64 + d) * SS + s0 + sc * 8) = o;
  }
}

// ---------------- Flash attention v2 ---------------------------------------
// Grid (S/64, B*H), 256 thr = 4 waves x 16 q-rows. KVBLK=64.
// Swapped QK^T: S^T = MFMA(K,Q) -> lane holds P^T[key=16kb+4g+j][q=c].
// Softmax in-register (per-lane q=c), P^T->A-frag via cvt_pk + shuffles.
// K and V^T tiles in LDS, XOR-swizzled (chunk ^= row&7) for bank-minimal b128.
__global__ __launch_bounds__(256) void attn_kernel(
    const unsigned short* __restrict__ Qb, const unsigned short* __restrict__ Kb,
    const unsigned short* __restrict__ Vt, const int* __restrict__ padMask,
    unsigned short* __restrict__ AO) {
  __shared__ unsigned short Ks[64 * 64];
  __shared__ unsigned short Vs[64 * 64];

  const int t = threadIdx.x;
  const int w = t >> 6, lane = t & 63;
  const int c = lane & 15, g = lane >> 4;
  const int a = g >> 1, bsel = g & 1;
  const int bh = blockIdx.y;
  const int b = bh >> 4, h = bh & 15;
  const int q0 = blockIdx.x * 64 + w * 16;
  const size_t baseBS = (size_t)b * SS;

  short8 aQ[2];
  {
    const unsigned short* qp = Qb + (baseBS + q0 + c) * DD + h * 64 + g * 8;
    aQ[0] = *(const short8*)(qp);
    aQ[1] = *(const short8*)(qp + 32);
  }
  const int qm = padMask[baseBS + q0 + c];

  float m_r = -1e30f, l_r = 0.f;
  f32x4 acc[4];
#pragma unroll
  for (int nb = 0; nb < 4; nb++) acc[nb] = {0.f, 0.f, 0.f, 0.f};

  for (int kt = 0; kt < SS / 64; ++kt) {
    const int kbase = kt * 64;
    // ---- stage K tile [key][d] and V^T tile [d][key], XOR-swizzled --------
#pragma unroll
    for (int i = 0; i < 2; i++) {
      int idx = t + i * 256;
      int r = idx >> 3, ch = idx & 7;
      int sw = (ch ^ (r & 7)) * 8;
      *(short8*)(Ks + r * 64 + sw) =
          *(const short8*)(Kb + (baseBS + kbase + r) * DD + h * 64 + ch * 8);
      *(short8*)(Vs + r * 64 + sw) =
          *(const short8*)(Vt + ((size_t)bh * 64 + r) * SS + kbase + ch * 8);
    }
    __syncthreads();

    // ---- S^T = MFMA(K, Q): sc[kb] reg j = S^T[key=16kb+4g+j][q0+c] --------
    f32x4 sc[4];
#pragma unroll
    for (int kb = 0; kb < 4; kb++) {
      f32x4 s = {0.f, 0.f, 0.f, 0.f};
#pragma unroll
      for (int kk = 0; kk < 2; kk++) {
        int row = kb * 16 + c;
        short8 ak = *(const short8*)(Ks + row * 64 + ((kk * 4 + g) ^ (c & 7)) * 8);
        s = MFMA(ak, aQ[kk], s);
      }
      sc[kb] = s;
    }

    // ---- mask + scale + online softmax (per-lane row q=c) -----------------
    float rm = -3e38f;
#pragma unroll
    for (int kb = 0; kb < 4; kb++) {
      int4 kmv = *(const int4*)(padMask + baseBS + kbase + kb * 16 + g * 4);
      int km[4] = {kmv.x, kmv.y, kmv.z, kmv.w};
#pragma unroll
      for (int j = 0; j < 4; j++) {
        float sv = (qm | km[j]) ? -1e8f : sc[kb][j] * 0.015625f;
        sc[kb][j] = sv;
        rm = fmaxf(rm, sv);
      }
    }
    rm = fmaxf(rm, __shfl_xor(rm, 16));
    rm = fmaxf(rm, __shfl_xor(rm, 32));
    const float mnew = fmaxf(m_r, rm);
    const float es = __expf(m_r - mnew);
    float sum = 0.f;
#pragma unroll
    for (int kb = 0; kb < 4; kb++)
#pragma unroll
      for (int j = 0; j < 4; j++) {
        float pv = __expf(sc[kb][j] - mnew);
        sc[kb][j] = pv;
        sum += pv;
      }
    sum += __shfl_xor(sum, 16);
    sum += __shfl_xor(sum, 32);
    l_r = l_r * es + sum;
    m_r = mnew;

    // rescale acc rows (acc reg j is q-row 4g+j; es lives in lane c=4g+j)
    float esj[4];
#pragma unroll
    for (int j = 0; j < 4; j++) esj[j] = __shfl(es, 4 * g + j);
#pragma unroll
    for (int nb = 0; nb < 4; nb++)
#pragma unroll
      for (int j = 0; j < 4; j++) acc[nb][j] *= esj[j];

    // ---- P^T (C-layout) -> PV A-frags, in-register ------------------------
    unsigned W0[4], W1[4];
#pragma unroll
    for (int kb = 0; kb < 4; kb++) {
      W0[kb] = cvtpk_bf16(sc[kb][0], sc[kb][1]);
      W1[kb] = cvtpk_bf16(sc[kb][2], sc[kb][3]);
    }
    const int srcA = c + (bsel << 5);   // lane (c, 2*(g&1))
    const int srcB = srcA + 16;         // lane (c, 2*(g&1)+1)
    unsigned A0[4], A1[4], B0[4], B1[4];
#pragma unroll
    for (int f = 0; f < 4; f++) {
      A0[f] = __shfl(W0[f], srcA);
      A1[f] = __shfl(W1[f], srcA);
      B0[f] = __shfl(W0[f], srcB);
      B1[f] = __shfl(W1[f], srcB);
    }
#pragma unroll
    for (int kk = 0; kk < 2; kk++) {
      u32x4 pd;
      pd.x = a ? A0[2 * kk + 1] : A0[2 * kk];
      pd.y = a ? A1[2 * kk + 1] : A1[2 * kk];
      pd.z = a ? B0[2 * kk + 1] : B0[2 * kk];
      pd.w = a ? B1[2 * kk + 1] : B1[2 * kk];
      short8 pa = __builtin_bit_cast(short8, pd);
#pragma unroll
      for (int nb = 0; nb < 4; nb++) {
        int row = nb * 16 + c;
        short8 vb_ = *(const short8*)(Vs + row * 64 + ((kk * 4 + g) ^ (c & 7)) * 8);
        acc[nb] = MFMA(pa, vb_, acc[nb]);
      }
    }
    __syncthreads();
  }

  float lj[4];
#pragma unroll
  for (int j = 0; j < 4; j++) lj[j] = __shfl(l_r, 4 * g + j);
#pragma unroll
  for (int nb = 0; nb < 4; nb++)
#pragma unroll
    for (int j = 0; j < 4; j++) {
      float ov = acc[nb][j] / lj[j];
      AO[(baseBS + q0 + 4 * g + j) * DD + h * 64 + nb * 16 + c] = f2bf(ov);
    }
}

extern "C" void kernel_launch(void* const* d_in, const int* in_sizes, int n_in,
                              void* d_out, int out_size, void* d_ws, size_t ws_size,
                              hipStream_t stream) {
  const float* enc = (const float*)d_in[0];
  const int* padMask = (const int*)d_in[1];
  const float* Wq = (const float*)d_in[2];
  const float* bq = (const float*)d_in[3];
  const float* Wk = (const float*)d_in[4];
  const float* bk = (const float*)d_in[5];
  const float* Wv = (const float*)d_in[6];
  const float* bv = (const float*)d_in[7];
  const float* Wo = (const float*)d_in[8];
  const float* bo = (const float*)d_in[9];
  float* out = (float*)d_out;

  const size_t NTOK = (size_t)4 * SS;      // 8192 rows
  unsigned short* Qb = (unsigned short*)d_ws;
  unsigned short* Kb = Qb + NTOK * DD;
  unsigned short* Vb = Kb + NTOK * DD;
  unsigned short* Vt = Vb + NTOK * DD;
  unsigned short* AO = Vb;                 // alias: Vb dead after transpose
  unsigned short* Ebf = Vt + NTOK * DD;
  unsigned short* Wqb = Ebf + NTOK * DD;
  unsigned short* Wkb = Wqb + (size_t)DD * DD;
  unsigned short* Wvb = Wkb + (size_t)DD * DD;
  unsigned short* Wob = Wvb + (size_t)DD * DD;

  const size_t need_ext =
      (5 * NTOK * DD + 4 * (size_t)DD * DD) * sizeof(unsigned short);
  const bool ext = ws_size >= need_ext;    // ws_size fixed per deployment

  dim3 blk(256);
  dim3 gGemm(DD / 128, NTOK / 128);        // (8, 64)
  dim3 gT(SS / 64, 4 * 16);                // (32, 64)

  if (ext) {
    const int n8e = (int)(NTOK * DD / 8);  // 1048576
    const int n8w = DD * DD / 8;           // 131072
    cvt_f32_bf16<<<n8e / 256, blk, 0, stream>>>(enc, Ebf, n8e);
    cvt_f32_bf16<<<n8w / 256, blk, 0, stream>>>(Wq, Wqb, n8w);
    cvt_f32_bf16<<<n8w / 256, blk, 0, stream>>>(Wk, Wkb, n8w);
    cvt_f32_bf16<<<n8w / 256, blk, 0, stream>>>(Wv, Wvb, n8w);
    cvt_f32_bf16<<<n8w / 256, blk, 0, stream>>>(Wo, Wob, n8w);
    gemm_bt<1, 1, 1><<<gGemm, blk, 0, stream>>>(Ebf, Wqb, bq, (void*)Qb);
    gemm_bt<1, 1, 1><<<gGemm, blk, 0, stream>>>(Ebf, Wkb, bk, (void*)Kb);
    gemm_bt<1, 1, 1><<<gGemm, blk, 0, stream>>>(Ebf, Wvb, bv, (void*)Vb);
    transpose_v<<<gT, blk, 0, stream>>>(Vb, Vt);
    attn_kernel<<<gT, blk, 0, stream>>>(Qb, Kb, Vt, padMask, AO);
    gemm_bt<1, 1, 0><<<gGemm, blk, 0, stream>>>(AO, Wob, bo, (void*)out);
  } else {
    gemm_bt<0, 0, 1><<<gGemm, blk, 0, stream>>>(enc, Wq, bq, (void*)Qb);
    gemm_bt<0, 0, 1><<<gGemm, blk, 0, stream>>>(enc, Wk, bk, (void*)Kb);
    gemm_bt<0, 0, 1><<<gGemm, blk, 0, stream>>>(enc, Wv, bv, (void*)Vb);
    transpose_v<<<gT, blk, 0, stream>>>(Vb, Vt);
    attn_kernel<<<gT, blk, 0, stream>>>(Qb, Kb, Vt, padMask, AO);
    gemm_bt<1, 0, 0><<<gGemm, blk, 0, stream>>>(AO, Wo, bo, (void*)out);
  }
}

// Round 9
// 379.745 us; speedup vs baseline: 1.5762x; 1.0761x over previous
//
#include <hip/hip_runtime.h>
#include <hip/hip_bf16.h>

// MHA for B=4, S=2048, D=1024, H=16, Dh=64.
// Pipeline: cvt fp32->bf16 (enc, 4x W) -> 3x bf16 GEMM (Q,K,V; Q pre-scaled by
// 1/64) -> V transpose -> flash attention (swapped QK^T, in-register softmax+P,
// LDS mask-bias table, defer-max, XOR-swizzled LDS) -> GEMM (AO@Wo^T+bo).
// GEMM bf16 path uses global_load_lds width-16 staging (m97 structure).
// ws: Qb,Kb,Vb,Vt + Ebf + 4xWbf = 92.3 MB (confirmed fits in R5); fp32
// fallback if smaller. AO aliases Vb.

#define SS 2048
#define DD 1024

typedef __attribute__((ext_vector_type(8))) short short8;
typedef __attribute__((ext_vector_type(8))) __bf16 bfv8;
typedef __attribute__((ext_vector_type(4))) float f32x4;
typedef __attribute__((ext_vector_type(4))) unsigned u32x4;

__device__ __forceinline__ unsigned short f2bf(float x) {
  unsigned u = __builtin_bit_cast(unsigned, x);
  u += 0x7fffu + ((u >> 16) & 1u);   // RNE
  return (unsigned short)(u >> 16);
}

__device__ __forceinline__ unsigned cvtpk_bf16(float lo, float hi) {
  unsigned r;
  asm("v_cvt_pk_bf16_f32 %0, %1, %2" : "=v"(r) : "v"(lo), "v"(hi));
  return r;
}

// async global->LDS, 16B per lane. lds dest must be wave-uniform base; HW adds
// lane*16. Casts go through integers (generic LDS ptr low 32 bits = offset).
__device__ __forceinline__ void gload_lds16(const void* gsrc, void* ldst) {
  __builtin_amdgcn_global_load_lds(
      (const __attribute__((address_space(1))) unsigned int*)(unsigned long long)gsrc,
      (__attribute__((address_space(3))) unsigned int*)(unsigned int)(unsigned long long)ldst,
      16, 0, 0);
}

// MFMA signature hedge (<8 x i16> vs <8 x bfloat> builds)
template <typename V>
__device__ __forceinline__ auto mfma_sel(V a, V b, f32x4 c, int)
    -> decltype(__builtin_amdgcn_mfma_f32_16x16x32_bf16(a, b, c, 0, 0, 0)) {
  return __builtin_amdgcn_mfma_f32_16x16x32_bf16(a, b, c, 0, 0, 0);
}
template <typename V>
__device__ __forceinline__ f32x4 mfma_sel(V a, V b, f32x4 c, long) {
  return __builtin_amdgcn_mfma_f32_16x16x32_bf16(
      __builtin_bit_cast(bfv8, a), __builtin_bit_cast(bfv8, b), c, 0, 0, 0);
}
__device__ __forceinline__ f32x4 MFMA(short8 a, short8 b, f32x4 c) {
  return mfma_sel(a, b, c, 0);
}

// ---------------- fp32 -> bf16 bulk converts --------------------------------
__global__ __launch_bounds__(256) void cvt_f32_bf16(
    const float* __restrict__ src, unsigned short* __restrict__ dst, int n8) {
  int i = blockIdx.x * blockDim.x + threadIdx.x;
  if (i < n8) {
    float4 a = ((const float4*)src)[2 * i];
    float4 b = ((const float4*)src)[2 * i + 1];
    short8 o;
    o[0] = f2bf(a.x); o[1] = f2bf(a.y); o[2] = f2bf(a.z); o[3] = f2bf(a.w);
    o[4] = f2bf(b.x); o[5] = f2bf(b.y); o[6] = f2bf(b.z); o[7] = f2bf(b.w);
    ((short8*)dst)[i] = o;
  }
}

// 4 weight matrices in one launch: grid (DD*DD/8/256, 4)
__global__ __launch_bounds__(256) void cvt_w4(
    const float* __restrict__ w0, const float* __restrict__ w1,
    const float* __restrict__ w2, const float* __restrict__ w3,
    unsigned short* __restrict__ o0, unsigned short* __restrict__ o1,
    unsigned short* __restrict__ o2, unsigned short* __restrict__ o3) {
  const float* s; unsigned short* d;
  switch (blockIdx.y) {
    case 0: s = w0; d = o0; break;
    case 1: s = w1; d = o1; break;
    case 2: s = w2; d = o2; break;
    default: s = w3; d = o3; break;
  }
  int i = blockIdx.x * blockDim.x + threadIdx.x;
  float4 a = ((const float4*)s)[2 * i];
  float4 b = ((const float4*)s)[2 * i + 1];
  short8 o;
  o[0] = f2bf(a.x); o[1] = f2bf(a.y); o[2] = f2bf(a.z); o[3] = f2bf(a.w);
  o[4] = f2bf(b.x); o[5] = f2bf(b.y); o[6] = f2bf(b.z); o[7] = f2bf(b.w);
  ((short8*)d)[i] = o;
}

// ---------------- GEMM: C[M,1024] = (A . W^T + bias) * oscale ---------------
// 128x128 tile, BK=32, 4 waves x (4x4) 16x16x32 MFMA frags.
// bf16xbf16 path: global_load_lds dwordx4 staging (m97). fp32 path: reg-staged.
template <int A_BF16, int W_BF16, int OUT_BF16>
__global__ __launch_bounds__(256) void gemm_bt(const void* __restrict__ Ain,
                                               const void* __restrict__ Win,
                                               const float* __restrict__ bias,
                                               void* __restrict__ Cout,
                                               float oscale) {
  __shared__ unsigned short As[128 * 32];
  __shared__ unsigned short Bs[128 * 32];
  const int t = threadIdx.x;
  const int lane = t & 63;
  const int w = t >> 6;
  const int l15 = lane & 15, g = lane >> 4;
  const int wr = w >> 1, wc = w & 1;
  const size_t m0 = (size_t)blockIdx.y * 128;
  const int n0 = blockIdx.x * 128;

  f32x4 acc[4][4];
#pragma unroll
  for (int i = 0; i < 4; i++)
#pragma unroll
    for (int j = 0; j < 4; j++) acc[i][j] = {0.f, 0.f, 0.f, 0.f};

  for (int k0 = 0; k0 < DD; k0 += 32) {
    if (A_BF16 && W_BF16) {
      const unsigned short* A = (const unsigned short*)Ain;
      const unsigned short* Wb = (const unsigned short*)Win;
#pragma unroll
      for (int i = 0; i < 2; i++) {
        int blk = i * 4 + w;                 // wave-uniform 0..7
        int row = blk * 16 + (lane >> 2);
        int c8 = lane & 3;
        gload_lds16(A + (m0 + row) * DD + k0 + c8 * 8, (char*)As + blk * 1024);
        gload_lds16(Wb + (size_t)(n0 + row) * DD + k0 + c8 * 8,
                    (char*)Bs + blk * 1024);
      }
    } else {
      if (A_BF16) {
        const unsigned short* A = (const unsigned short*)Ain;
#pragma unroll
        for (int i = 0; i < 2; i++) {
          int idx = t + i * 256;
          int row = idx >> 2, c8 = idx & 3;
          *(short8*)(As + row * 32 + c8 * 8) =
              *(const short8*)(A + (m0 + row) * DD + k0 + c8 * 8);
        }
      } else {
        const float* A = (const float*)Ain;
#pragma unroll
        for (int i = 0; i < 4; i++) {
          int idx = t + i * 256;
          int row = idx >> 3, c4 = idx & 7;
          float4 v = *(const float4*)(A + (m0 + row) * DD + k0 + c4 * 4);
          ushort4 o = {f2bf(v.x), f2bf(v.y), f2bf(v.z), f2bf(v.w)};
          *(ushort4*)(As + row * 32 + c4 * 4) = o;
        }
      }
      const float* Wf = (const float*)Win;
#pragma unroll
      for (int i = 0; i < 4; i++) {
        int idx = t + i * 256;
        int row = idx >> 3, c4 = idx & 7;
        float4 v = *(const float4*)(Wf + (size_t)(n0 + row) * DD + k0 + c4 * 4);
        ushort4 o = {f2bf(v.x), f2bf(v.y), f2bf(v.z), f2bf(v.w)};
        *(ushort4*)(Bs + row * 32 + c4 * 4) = o;
      }
    }
    __syncthreads();
    short8 af[4], bfr[4];
#pragma unroll
    for (int mi = 0; mi < 4; mi++)
      af[mi] = *(const short8*)(As + (wr * 64 + mi * 16 + l15) * 32 + g * 8);
#pragma unroll
    for (int ni = 0; ni < 4; ni++)
      bfr[ni] = *(const short8*)(Bs + (wc * 64 + ni * 16 + l15) * 32 + g * 8);
#pragma unroll
    for (int mi = 0; mi < 4; mi++)
#pragma unroll
      for (int ni = 0; ni < 4; ni++)
        acc[mi][ni] = MFMA(af[mi], bfr[ni], acc[mi][ni]);
    __syncthreads();
  }

  float bs[4];
#pragma unroll
  for (int ni = 0; ni < 4; ni++) bs[ni] = bias[n0 + wc * 64 + ni * 16 + l15];
#pragma unroll
  for (int mi = 0; mi < 4; mi++) {
#pragma unroll
    for (int ni = 0; ni < 4; ni++) {
      size_t row = m0 + wr * 64 + mi * 16 + g * 4;
      int col = n0 + wc * 64 + ni * 16 + l15;
#pragma unroll
      for (int j = 0; j < 4; j++) {
        float v = (acc[mi][ni][j] + bs[ni]) * oscale;
        if (OUT_BF16)
          ((unsigned short*)Cout)[(row + j) * DD + col] = f2bf(v);
        else
          ((float*)Cout)[(row + j) * DD + col] = v;
      }
    }
  }
}

// ---------------- V transpose: Vb[b*S+s][h*64+d] -> Vt[(bh*64+d)][s] --------
__global__ __launch_bounds__(256) void transpose_v(
    const unsigned short* __restrict__ Vb, unsigned short* __restrict__ Vt) {
  __shared__ unsigned short L[64 * 72];
  const int t = threadIdx.x;
  const int s0 = blockIdx.x * 64;
  const int bh = blockIdx.y;
  const int b = bh >> 4, h = bh & 15;
#pragma unroll
  for (int i = 0; i < 2; i++) {
    int idx = t + i * 256;
    int s = idx >> 3, dc = idx & 7;
    *(short8*)(L + s * 72 + dc * 8) =
        *(const short8*)(Vb + ((size_t)b * SS + s0 + s) * DD + h * 64 + dc * 8);
  }
  __syncthreads();
#pragma unroll
  for (int i = 0; i < 2; i++) {
    int idx = t + i * 256;
    int d = idx >> 3, sc = idx & 7;
    short8 o;
#pragma unroll
    for (int e = 0; e < 8; e++) o[e] = (short)L[(sc * 8 + e) * 72 + d];
    *(short8*)(Vt + ((size_t)bh * 64 + d) * SS + s0 + sc * 8) = o;
  }
}

// ---------------- Flash attention v3 ---------------------------------------
// Grid (S/64, B*H), 256 thr = 4 waves x 16 q-rows. KVBLK=64.
// Swapped QK^T: S^T = MFMA(K,Q) -> lane holds P^T[key=16kb+4g+j][q=c].
// Q pre-scaled by 1/64 in its GEMM. Mask via per-block LDS float-bias table
// (masked -1e8 / unmasked +3e38) + single fmin per element (exact -1e8
// semantics). Defer-max (T13, thr=8) skips rescale on non-growing tiles.
__global__ __launch_bounds__(256) void attn_kernel(
    const unsigned short* __restrict__ Qb, const unsigned short* __restrict__ Kb,
    const unsigned short* __restrict__ Vt, const int* __restrict__ padMask,
    unsigned short* __restrict__ AO) {
  __shared__ unsigned short Ks[64 * 64];
  __shared__ unsigned short Vs[64 * 64];
  __shared__ float KmB[SS];   // 8KB: key mask bias for the whole sequence

  const int t = threadIdx.x;
  const int w = t >> 6, lane = t & 63;
  const int c = lane & 15, g = lane >> 4;
  const int a = g >> 1, bsel = g & 1;
  const int bh = blockIdx.y;
  const int b = bh >> 4, h = bh & 15;
  const int q0 = blockIdx.x * 64 + w * 16;
  const size_t baseBS = (size_t)b * SS;

  // ---- per-block: key mask -> float bias table in LDS ----------------------
  {
    int4 ma = *(const int4*)(padMask + baseBS + t * 8);
    int4 mb = *(const int4*)(padMask + baseBS + t * 8 + 4);
    float4 fa = {ma.x ? -1e8f : 3e38f, ma.y ? -1e8f : 3e38f,
                 ma.z ? -1e8f : 3e38f, ma.w ? -1e8f : 3e38f};
    float4 fb = {mb.x ? -1e8f : 3e38f, mb.y ? -1e8f : 3e38f,
                 mb.z ? -1e8f : 3e38f, mb.w ? -1e8f : 3e38f};
    *(float4*)(KmB + t * 8) = fa;
    *(float4*)(KmB + t * 8 + 4) = fb;
  }

  short8 aQ[2];
  {
    const unsigned short* qp = Qb + (baseBS + q0 + c) * DD + h * 64 + g * 8;
    aQ[0] = *(const short8*)(qp);
    aQ[1] = *(const short8*)(qp + 32);
  }
  const float qmf = padMask[baseBS + q0 + c] ? -1e8f : 3e38f;

  float m_r = -1e30f, l_r = 0.f;
  f32x4 acc[4];
#pragma unroll
  for (int nb = 0; nb < 4; nb++) acc[nb] = {0.f, 0.f, 0.f, 0.f};

  for (int kt = 0; kt < SS / 64; ++kt) {
    const int kbase = kt * 64;
    // ---- stage K tile [key][d] and V^T tile [d][key], XOR-swizzled --------
#pragma unroll
    for (int i = 0; i < 2; i++) {
      int idx = t + i * 256;
      int r = idx >> 3, ch = idx & 7;
      int sw = (ch ^ (r & 7)) * 8;
      *(short8*)(Ks + r * 64 + sw) =
          *(const short8*)(Kb + (baseBS + kbase + r) * DD + h * 64 + ch * 8);
      *(short8*)(Vs + r * 64 + sw) =
          *(const short8*)(Vt + ((size_t)bh * 64 + r) * SS + kbase + ch * 8);
    }
    __syncthreads();

    // ---- S^T = MFMA(K, Q): sc[kb] reg j = S^T[key=16kb+4g+j][q0+c] --------
    f32x4 sc[4];
#pragma unroll
    for (int kb = 0; kb < 4; kb++) {
      f32x4 s = {0.f, 0.f, 0.f, 0.f};
#pragma unroll
      for (int kk = 0; kk < 2; kk++) {
        int row = kb * 16 + c;
        short8 ak = *(const short8*)(Ks + row * 64 + ((kk * 4 + g) ^ (c & 7)) * 8);
        s = MFMA(ak, aQ[kk], s);
      }
      sc[kb] = s;
    }

    // ---- mask (single fmin) + online softmax (per-lane row q=c) -----------
    f32x4 kmf[4];
#pragma unroll
    for (int kb = 0; kb < 4; kb++)
      kmf[kb] = *(const f32x4*)(KmB + kbase + kb * 16 + g * 4);

    float rm = -3e38f;
#pragma unroll
    for (int kb = 0; kb < 4; kb++)
#pragma unroll
      for (int j = 0; j < 4; j++) {
        float sv = fminf(fminf(sc[kb][j], kmf[kb][j]), qmf);
        sc[kb][j] = sv;
        rm = fmaxf(rm, sv);
      }
    rm = fmaxf(rm, __shfl_xor(rm, 16));
    rm = fmaxf(rm, __shfl_xor(rm, 32));

    const bool grow = !__all(rm <= m_r + 8.f);   // wave-uniform
    const float mnew = grow ? fmaxf(m_r, rm) : m_r;
    float sum = 0.f;
#pragma unroll
    for (int kb = 0; kb < 4; kb++)
#pragma unroll
      for (int j = 0; j < 4; j++) {
        float pv = __expf(sc[kb][j] - mnew);
        sc[kb][j] = pv;
        sum += pv;
      }
    sum += __shfl_xor(sum, 16);
    sum += __shfl_xor(sum, 32);
    if (grow) {
      const float es = __expf(m_r - mnew);
      l_r = l_r * es + sum;
      m_r = mnew;
      float esj[4];
#pragma unroll
      for (int j = 0; j < 4; j++) esj[j] = __shfl(es, 4 * g + j);
#pragma unroll
      for (int nb = 0; nb < 4; nb++)
#pragma unroll
        for (int j = 0; j < 4; j++) acc[nb][j] *= esj[j];
    } else {
      l_r += sum;
    }

    // ---- P^T (C-layout) -> PV A-frags, in-register ------------------------
    unsigned W0[4], W1[4];
#pragma unroll
    for (int kb = 0; kb < 4; kb++) {
      W0[kb] = cvtpk_bf16(sc[kb][0], sc[kb][1]);
      W1[kb] = cvtpk_bf16(sc[kb][2], sc[kb][3]);
    }
    const int srcA = c + (bsel << 5);
    const int srcB = srcA + 16;
    unsigned A0[4], A1[4], B0[4], B1[4];
#pragma unroll
    for (int f = 0; f < 4; f++) {
      A0[f] = __shfl(W0[f], srcA);
      A1[f] = __shfl(W1[f], srcA);
      B0[f] = __shfl(W0[f], srcB);
      B1[f] = __shfl(W1[f], srcB);
    }
#pragma unroll
    for (int kk = 0; kk < 2; kk++) {
      u32x4 pd;
      pd.x = a ? A0[2 * kk + 1] : A0[2 * kk];
      pd.y = a ? A1[2 * kk + 1] : A1[2 * kk];
      pd.z = a ? B0[2 * kk + 1] : B0[2 * kk];
      pd.w = a ? B1[2 * kk + 1] : B1[2 * kk];
      short8 pa = __builtin_bit_cast(short8, pd);
#pragma unroll
      for (int nb = 0; nb < 4; nb++) {
        int row = nb * 16 + c;
        short8 vb_ = *(const short8*)(Vs + row * 64 + ((kk * 4 + g) ^ (c & 7)) * 8);
        acc[nb] = MFMA(pa, vb_, acc[nb]);
      }
    }
    __syncthreads();
  }

  float lj[4];
#pragma unroll
  for (int j = 0; j < 4; j++) lj[j] = __shfl(l_r, 4 * g + j);
#pragma unroll
  for (int nb = 0; nb < 4; nb++)
#pragma unroll
    for (int j = 0; j < 4; j++) {
      float ov = acc[nb][j] / lj[j];
      AO[(baseBS + q0 + 4 * g + j) * DD + h * 64 + nb * 16 + c] = f2bf(ov);
    }
}

extern "C" void kernel_launch(void* const* d_in, const int* in_sizes, int n_in,
                              void* d_out, int out_size, void* d_ws, size_t ws_size,
                              hipStream_t stream) {
  const float* enc = (const float*)d_in[0];
  const int* padMask = (const int*)d_in[1];
  const float* Wq = (const float*)d_in[2];
  const float* bq = (const float*)d_in[3];
  const float* Wk = (const float*)d_in[4];
  const float* bk = (const float*)d_in[5];
  const float* Wv = (const float*)d_in[6];
  const float* bv = (const float*)d_in[7];
  const float* Wo = (const float*)d_in[8];
  const float* bo = (const float*)d_in[9];
  float* out = (float*)d_out;

  const size_t NTOK = (size_t)4 * SS;      // 8192 rows
  unsigned short* Qb = (unsigned short*)d_ws;
  unsigned short* Kb = Qb + NTOK * DD;
  unsigned short* Vb = Kb + NTOK * DD;
  unsigned short* Vt = Vb + NTOK * DD;
  unsigned short* AO = Vb;                 // alias: Vb dead after transpose
  unsigned short* Ebf = Vt + NTOK * DD;
  unsigned short* Wqb = Ebf + NTOK * DD;
  unsigned short* Wkb = Wqb + (size_t)DD * DD;
  unsigned short* Wvb = Wkb + (size_t)DD * DD;
  unsigned short* Wob = Wvb + (size_t)DD * DD;

  const size_t need_ext =
      (5 * NTOK * DD + 4 * (size_t)DD * DD) * sizeof(unsigned short);
  const bool ext = ws_size >= need_ext;    // fixed per deployment

  const float QSC = 0.015625f;             // 1/64 folded into Q
  dim3 blk(256);
  dim3 gGemm(DD / 128, NTOK / 128);        // (8, 64)
  dim3 gT(SS / 64, 4 * 16);                // (32, 64)

  if (ext) {
    const int n8e = (int)(NTOK * DD / 8);  // 1048576
    const int n8w = DD * DD / 8;           // 131072
    cvt_f32_bf16<<<n8e / 256, blk, 0, stream>>>(enc, Ebf, n8e);
    cvt_w4<<<dim3(n8w / 256, 4), blk, 0, stream>>>(Wq, Wk, Wv, Wo,
                                                   Wqb, Wkb, Wvb, Wob);
    gemm_bt<1, 1, 1><<<gGemm, blk, 0, stream>>>(Ebf, Wqb, bq, (void*)Qb, QSC);
    gemm_bt<1, 1, 1><<<gGemm, blk, 0, stream>>>(Ebf, Wkb, bk, (void*)Kb, 1.f);
    gemm_bt<1, 1, 1><<<gGemm, blk, 0, stream>>>(Ebf, Wvb, bv, (void*)Vb, 1.f);
    transpose_v<<<gT, blk, 0, stream>>>(Vb, Vt);
    attn_kernel<<<gT, blk, 0, stream>>>(Qb, Kb, Vt, padMask, AO);
    gemm_bt<1, 1, 0><<<gGemm, blk, 0, stream>>>(AO, Wob, bo, (void*)out, 1.f);
  } else {
    gemm_bt<0, 0, 1><<<gGemm, blk, 0, stream>>>(enc, Wq, bq, (void*)Qb, QSC);
    gemm_bt<0, 0, 1><<<gGemm, blk, 0, stream>>>(enc, Wk, bk, (void*)Kb, 1.f);
    gemm_bt<0, 0, 1><<<gGemm, blk, 0, stream>>>(enc, Wv, bv, (void*)Vb, 1.f);
    transpose_v<<<gT, blk, 0, stream>>>(Vb, Vt);
    attn_kernel<<<gT, blk, 0, stream>>>(Qb, Kb, Vt, padMask, AO);
    gemm_bt<1, 0, 0><<<gGemm, blk, 0, stream>>>(AO, Wo, bo, (void*)out, 1.f);
  }
}

// Round 11
// 326.415 us; speedup vs baseline: 1.8338x; 1.1634x over previous
//
#include <hip/hip_runtime.h>
#include <hip/hip_bf16.h>

// MHA for B=4, S=2048, D=1024, H=16, Dh=64.
// Pipeline: cvt fp32->bf16 -> fused QKV GEMM (XCD-swizzled, Q pre-scaled by
// log2e/64) -> V transpose -> flash attention (swapped QK^T, exp2 softmax,
// O^T PV via wave-private LDS P-bounce, defer-max) -> out GEMM (XCD-swizzled).
// ws: Qb,Kb,Vb,Vt + Ebf + 4xWbf = 92.3 MB (confirmed); fp32 fallback if less.

#define SS 2048
#define DD 1024
#define MM 8192   // total tokens (4*SS)

typedef __attribute__((ext_vector_type(8))) short short8;
typedef __attribute__((ext_vector_type(8))) __bf16 bfv8;
typedef __attribute__((ext_vector_type(4))) float f32x4;
typedef __attribute__((ext_vector_type(4))) unsigned u32x4;
typedef __attribute__((ext_vector_type(2))) unsigned u32x2;
typedef __attribute__((ext_vector_type(4))) unsigned short us4;

#define LOG2E 1.4426950408889634f
#define NEGB (-1.44269504e8f)   // -1e8 * log2e (exact -1e8 semantics in exp2 space)

__device__ __forceinline__ unsigned short f2bf(float x) {
  unsigned u = __builtin_bit_cast(unsigned, x);
  u += 0x7fffu + ((u >> 16) & 1u);   // RNE
  return (unsigned short)(u >> 16);
}

__device__ __forceinline__ unsigned cvtpk_bf16(float lo, float hi) {
  unsigned r;
  asm("v_cvt_pk_bf16_f32 %0, %1, %2" : "=v"(r) : "v"(lo), "v"(hi));
  return r;
}

__device__ __forceinline__ float exp2_hw(float x) {
  float r;
  asm("v_exp_f32 %0, %1" : "=v"(r) : "v"(x));
  return r;
}

// async global->LDS, 16B per lane: dest = wave-uniform base + lane*16.
__device__ __forceinline__ void gload_lds16(const void* gsrc, void* ldst) {
  __builtin_amdgcn_global_load_lds(
      (const __attribute__((address_space(1))) unsigned int*)(unsigned long long)gsrc,
      (__attribute__((address_space(3))) unsigned int*)(unsigned int)(unsigned long long)ldst,
      16, 0, 0);
}

// MFMA signature hedge (<8 x i16> vs <8 x bfloat> builds)
template <typename V>
__device__ __forceinline__ auto mfma_sel(V a, V b, f32x4 c, int)
    -> decltype(__builtin_amdgcn_mfma_f32_16x16x32_bf16(a, b, c, 0, 0, 0)) {
  return __builtin_amdgcn_mfma_f32_16x16x32_bf16(a, b, c, 0, 0, 0);
}
template <typename V>
__device__ __forceinline__ f32x4 mfma_sel(V a, V b, f32x4 c, long) {
  return __builtin_amdgcn_mfma_f32_16x16x32_bf16(
      __builtin_bit_cast(bfv8, a), __builtin_bit_cast(bfv8, b), c, 0, 0, 0);
}
__device__ __forceinline__ f32x4 MFMA(short8 a, short8 b, f32x4 c) {
  return mfma_sel(a, b, c, 0);
}

// ---------------- fp32 -> bf16 bulk converts --------------------------------
__global__ __launch_bounds__(256) void cvt_f32_bf16(
    const float* __restrict__ src, unsigned short* __restrict__ dst, int n8) {
  int i = blockIdx.x * blockDim.x + threadIdx.x;
  if (i < n8) {
    float4 a = ((const float4*)src)[2 * i];
    float4 b = ((const float4*)src)[2 * i + 1];
    short8 o;
    o[0] = f2bf(a.x); o[1] = f2bf(a.y); o[2] = f2bf(a.z); o[3] = f2bf(a.w);
    o[4] = f2bf(b.x); o[5] = f2bf(b.y); o[6] = f2bf(b.z); o[7] = f2bf(b.w);
    ((short8*)dst)[i] = o;
  }
}

__global__ __launch_bounds__(256) void cvt_w4(
    const float* __restrict__ w0, const float* __restrict__ w1,
    const float* __restrict__ w2, const float* __restrict__ w3,
    unsigned short* __restrict__ o0, unsigned short* __restrict__ o1,
    unsigned short* __restrict__ o2, unsigned short* __restrict__ o3) {
  const float* s; unsigned short* d;
  switch (blockIdx.y) {
    case 0: s = w0; d = o0; break;
    case 1: s = w1; d = o1; break;
    case 2: s = w2; d = o2; break;
    default: s = w3; d = o3; break;
  }
  int i = blockIdx.x * blockDim.x + threadIdx.x;
  float4 a = ((const float4*)s)[2 * i];
  float4 b = ((const float4*)s)[2 * i + 1];
  short8 o;
  o[0] = f2bf(a.x); o[1] = f2bf(a.y); o[2] = f2bf(a.z); o[3] = f2bf(a.w);
  o[4] = f2bf(b.x); o[5] = f2bf(b.y); o[6] = f2bf(b.z); o[7] = f2bf(b.w);
  ((short8*)d)[i] = o;
}

// ---------------- XCD-swizzled GEMM, bf16 x bf16 (ext path) -----------------
// C[mat][MM,1024] = (A . W[mat]^T + bias[mat]) * osc[mat].
// Grid = NMATS*8*64 1-D blocks. Decode: xcd = bid%8 owns contiguous 8 m-blocks
// (A chunk 2MB stays L2-resident), n fastest within XCD (W tile streamed once).
template <int NMATS, int OUT_BF16>
__global__ __launch_bounds__(256) void gemm_swz(
    const unsigned short* __restrict__ A, const unsigned short* __restrict__ Wall,
    const float* __restrict__ b0, const float* __restrict__ b1,
    const float* __restrict__ b2, void* __restrict__ Cout,
    float s0, float s1, float s2) {
  __shared__ unsigned short As[128 * 32];
  __shared__ unsigned short Bs[128 * 32];
  const int bid = blockIdx.x;
  const int xcd = bid & 7, q = bid >> 3;
  const int n_blk = q >> 3;                      // 0..NMATS*8-1
  const int m_blk = (xcd << 3) + (q & 7);        // 0..63
  const int mat = (NMATS == 3) ? (n_blk >> 3) : 0;
  const int n0 = (NMATS == 3) ? ((n_blk & 7) * 128) : (n_blk * 128);
  const unsigned short* Wb = Wall + (size_t)mat * DD * DD;
  const float* bias = (mat == 0) ? b0 : (mat == 1 ? b1 : b2);
  const float osc = (mat == 0) ? s0 : (mat == 1 ? s1 : s2);
  const size_t m0 = (size_t)m_blk * 128;

  const int t = threadIdx.x;
  const int lane = t & 63;
  const int w = t >> 6;
  const int l15 = lane & 15, g = lane >> 4;
  const int wr = w >> 1, wc = w & 1;

  f32x4 acc[4][4];
#pragma unroll
  for (int i = 0; i < 4; i++)
#pragma unroll
    for (int j = 0; j < 4; j++) acc[i][j] = {0.f, 0.f, 0.f, 0.f};

  for (int k0 = 0; k0 < DD; k0 += 32) {
#pragma unroll
    for (int i = 0; i < 2; i++) {
      int blk = i * 4 + w;                 // wave-uniform 0..7
      int row = blk * 16 + (lane >> 2);
      int c8 = lane & 3;
      gload_lds16(A + (m0 + row) * DD + k0 + c8 * 8, (char*)As + blk * 1024);
      gload_lds16(Wb + (size_t)(n0 + row) * DD + k0 + c8 * 8,
                  (char*)Bs + blk * 1024);
    }
    __syncthreads();
    short8 af[4], bfr[4];
#pragma unroll
    for (int mi = 0; mi < 4; mi++)
      af[mi] = *(const short8*)(As + (wr * 64 + mi * 16 + l15) * 32 + g * 8);
#pragma unroll
    for (int ni = 0; ni < 4; ni++)
      bfr[ni] = *(const short8*)(Bs + (wc * 64 + ni * 16 + l15) * 32 + g * 8);
#pragma unroll
    for (int mi = 0; mi < 4; mi++)
#pragma unroll
      for (int ni = 0; ni < 4; ni++)
        acc[mi][ni] = MFMA(af[mi], bfr[ni], acc[mi][ni]);
    __syncthreads();
  }

  float bs[4];
#pragma unroll
  for (int ni = 0; ni < 4; ni++) bs[ni] = bias[n0 + wc * 64 + ni * 16 + l15];
#pragma unroll
  for (int mi = 0; mi < 4; mi++) {
#pragma unroll
    for (int ni = 0; ni < 4; ni++) {
      size_t row = m0 + wr * 64 + mi * 16 + g * 4;
      int col = n0 + wc * 64 + ni * 16 + l15;
#pragma unroll
      for (int j = 0; j < 4; j++) {
        float v = (acc[mi][ni][j] + bs[ni]) * osc;
        if (OUT_BF16)
          ((unsigned short*)Cout + (size_t)mat * MM * DD)[(row + j) * DD + col] =
              f2bf(v);
        else
          ((float*)Cout)[(row + j) * DD + col] = v;
      }
    }
  }
}

// ---------------- legacy GEMM (fp32 fallback path only) ---------------------
template <int A_BF16, int OUT_BF16>
__global__ __launch_bounds__(256) void gemm_bt(const void* __restrict__ Ain,
                                               const float* __restrict__ Wf,
                                               const float* __restrict__ bias,
                                               void* __restrict__ Cout,
                                               float oscale) {
  __shared__ unsigned short As[128 * 32];
  __shared__ unsigned short Bs[128 * 32];
  const int t = threadIdx.x;
  const int lane = t & 63;
  const int w = t >> 6;
  const int l15 = lane & 15, g = lane >> 4;
  const int wr = w >> 1, wc = w & 1;
  const size_t m0 = (size_t)blockIdx.y * 128;
  const int n0 = blockIdx.x * 128;

  f32x4 acc[4][4];
#pragma unroll
  for (int i = 0; i < 4; i++)
#pragma unroll
    for (int j = 0; j < 4; j++) acc[i][j] = {0.f, 0.f, 0.f, 0.f};

  for (int k0 = 0; k0 < DD; k0 += 32) {
    if (A_BF16) {
      const unsigned short* A = (const unsigned short*)Ain;
#pragma unroll
      for (int i = 0; i < 2; i++) {
        int idx = t + i * 256;
        int row = idx >> 2, c8 = idx & 3;
        *(short8*)(As + row * 32 + c8 * 8) =
            *(const short8*)(A + (m0 + row) * DD + k0 + c8 * 8);
      }
    } else {
      const float* A = (const float*)Ain;
#pragma unroll
      for (int i = 0; i < 4; i++) {
        int idx = t + i * 256;
        int row = idx >> 3, c4 = idx & 7;
        float4 v = *(const float4*)(A + (m0 + row) * DD + k0 + c4 * 4);
        ushort4 o = {f2bf(v.x), f2bf(v.y), f2bf(v.z), f2bf(v.w)};
        *(ushort4*)(As + row * 32 + c4 * 4) = o;
      }
    }
    const float* Wp = Wf;
#pragma unroll
    for (int i = 0; i < 4; i++) {
      int idx = t + i * 256;
      int row = idx >> 3, c4 = idx & 7;
      float4 v = *(const float4*)(Wp + (size_t)(n0 + row) * DD + k0 + c4 * 4);
      ushort4 o = {f2bf(v.x), f2bf(v.y), f2bf(v.z), f2bf(v.w)};
      *(ushort4*)(Bs + row * 32 + c4 * 4) = o;
    }
    __syncthreads();
    short8 af[4], bfr[4];
#pragma unroll
    for (int mi = 0; mi < 4; mi++)
      af[mi] = *(const short8*)(As + (wr * 64 + mi * 16 + l15) * 32 + g * 8);
#pragma unroll
    for (int ni = 0; ni < 4; ni++)
      bfr[ni] = *(const short8*)(Bs + (wc * 64 + ni * 16 + l15) * 32 + g * 8);
#pragma unroll
    for (int mi = 0; mi < 4; mi++)
#pragma unroll
      for (int ni = 0; ni < 4; ni++)
        acc[mi][ni] = MFMA(af[mi], bfr[ni], acc[mi][ni]);
    __syncthreads();
  }

  float bs[4];
#pragma unroll
  for (int ni = 0; ni < 4; ni++) bs[ni] = bias[n0 + wc * 64 + ni * 16 + l15];
#pragma unroll
  for (int mi = 0; mi < 4; mi++) {
#pragma unroll
    for (int ni = 0; ni < 4; ni++) {
      size_t row = m0 + wr * 64 + mi * 16 + g * 4;
      int col = n0 + wc * 64 + ni * 16 + l15;
#pragma unroll
      for (int j = 0; j < 4; j++) {
        float v = (acc[mi][ni][j] + bs[ni]) * oscale;
        if (OUT_BF16)
          ((unsigned short*)Cout)[(row + j) * DD + col] = f2bf(v);
        else
          ((float*)Cout)[(row + j) * DD + col] = v;
      }
    }
  }
}

// ---------------- V transpose: Vb[b*S+s][h*64+d] -> Vt[(bh*64+d)][s] --------
__global__ __launch_bounds__(256) void transpose_v(
    const unsigned short* __restrict__ Vb, unsigned short* __restrict__ Vt) {
  __shared__ unsigned short L[64 * 72];
  const int t = threadIdx.x;
  const int s0 = blockIdx.x * 64;
  const int bh = blockIdx.y;
  const int b = bh >> 4, h = bh & 15;
#pragma unroll
  for (int i = 0; i < 2; i++) {
    int idx = t + i * 256;
    int s = idx >> 3, dc = idx & 7;
    *(short8*)(L + s * 72 + dc * 8) =
        *(const short8*)(Vb + ((size_t)b * SS + s0 + s) * DD + h * 64 + dc * 8);
  }
  __syncthreads();
#pragma unroll
  for (int i = 0; i < 2; i++) {
    int idx = t + i * 256;
    int d = idx >> 3, sc = idx & 7;
    short8 o;
#pragma unroll
    for (int e = 0; e < 8; e++) o[e] = (short)L[(sc * 8 + e) * 72 + d];
    *(short8*)(Vt + ((size_t)bh * 64 + d) * SS + s0 + sc * 8) = o;
  }
}

// ---------------- Flash attention v4 ---------------------------------------
// Grid (S/64, B*H), 256 thr = 4 waves x 16 q-rows. KVBLK=64. exp2 space
// (Q pre-scaled by log2e/64; biases by log2e). Swapped QK^T: sc[kb][j] =
// S^T[key=16kb+4g+j][q=c]. O^T PV: O^T = MFMA(A=V^T, B=P^T) so acc is
// q=c-aligned (no shuffles for rescale/divide). P^T -> B-frag via wave-private
// XOR-swizzled LDS (4 ds_write_b64 + 2 ds_read_b128 per tile).
__global__ __launch_bounds__(256) void attn_kernel(
    const unsigned short* __restrict__ Qb, const unsigned short* __restrict__ Kb,
    const unsigned short* __restrict__ Vt, const int* __restrict__ padMask,
    unsigned short* __restrict__ AO) {
  __shared__ unsigned short Ks[64 * 64];
  __shared__ unsigned short Vs[64 * 64];
  __shared__ float KmB[SS];          // 8KB key-mask bias (exp2 space)
  __shared__ unsigned Ps[4 * 512];   // 8KB: per-wave 512-dword P bounce

  const int t = threadIdx.x;
  const int w = t >> 6, lane = t & 63;
  const int c = lane & 15, g = lane >> 4;
  const int bh = blockIdx.y;
  const int b = bh >> 4, h = bh & 15;
  const int q0 = blockIdx.x * 64 + w * 16;
  const size_t baseBS = (size_t)b * SS;

  {
    int4 ma = *(const int4*)(padMask + baseBS + t * 8);
    int4 mb = *(const int4*)(padMask + baseBS + t * 8 + 4);
    float4 fa = {ma.x ? NEGB : 3e38f, ma.y ? NEGB : 3e38f,
                 ma.z ? NEGB : 3e38f, ma.w ? NEGB : 3e38f};
    float4 fb = {mb.x ? NEGB : 3e38f, mb.y ? NEGB : 3e38f,
                 mb.z ? NEGB : 3e38f, mb.w ? NEGB : 3e38f};
    *(float4*)(KmB + t * 8) = fa;
    *(float4*)(KmB + t * 8 + 4) = fb;
  }

  short8 aQ[2];
  {
    const unsigned short* qp = Qb + (baseBS + q0 + c) * DD + h * 64 + g * 8;
    aQ[0] = *(const short8*)(qp);
    aQ[1] = *(const short8*)(qp + 32);
  }
  const float qmf = padMask[baseBS + q0 + c] ? NEGB : 3e38f;
  const int cx = (c & 7) << 2;       // XOR swizzle for P bounce (dword units)
  unsigned* Pw = Ps + w * 512;

  float m_r = -1e30f, l_r = 0.f;
  f32x4 acc[4];
#pragma unroll
  for (int nb = 0; nb < 4; nb++) acc[nb] = {0.f, 0.f, 0.f, 0.f};

  for (int kt = 0; kt < SS / 64; ++kt) {
    const int kbase = kt * 64;
#pragma unroll
    for (int i = 0; i < 2; i++) {
      int idx = t + i * 256;
      int r = idx >> 3, ch = idx & 7;
      int sw = (ch ^ (r & 7)) * 8;
      *(short8*)(Ks + r * 64 + sw) =
          *(const short8*)(Kb + (baseBS + kbase + r) * DD + h * 64 + ch * 8);
      *(short8*)(Vs + r * 64 + sw) =
          *(const short8*)(Vt + ((size_t)bh * 64 + r) * SS + kbase + ch * 8);
    }
    __syncthreads();

    // ---- S^T = MFMA(K, Q) -------------------------------------------------
    f32x4 sc[4];
#pragma unroll
    for (int kb = 0; kb < 4; kb++) {
      f32x4 s = {0.f, 0.f, 0.f, 0.f};
#pragma unroll
      for (int kk = 0; kk < 2; kk++) {
        int row = kb * 16 + c;
        short8 ak = *(const short8*)(Ks + row * 64 + ((kk * 4 + g) ^ (c & 7)) * 8);
        s = MFMA(ak, aQ[kk], s);
      }
      sc[kb] = s;
    }

    // ---- mask + online softmax (exp2 space, per-lane q=c) -----------------
    f32x4 kmf[4];
#pragma unroll
    for (int kb = 0; kb < 4; kb++)
      kmf[kb] = *(const f32x4*)(KmB + kbase + kb * 16 + g * 4);

    float rm = -3e38f;
#pragma unroll
    for (int kb = 0; kb < 4; kb++)
#pragma unroll
      for (int j = 0; j < 4; j++) {
        float sv = fminf(fminf(sc[kb][j], kmf[kb][j]), qmf);
        sc[kb][j] = sv;
        rm = fmaxf(rm, sv);
      }
    rm = fmaxf(rm, __shfl_xor(rm, 16));
    rm = fmaxf(rm, __shfl_xor(rm, 32));

    const bool grow = !__all(rm <= m_r + 11.5f);   // 8*log2e, wave-uniform
    const float mnew = grow ? fmaxf(m_r, rm) : m_r;
    float sum = 0.f;
#pragma unroll
    for (int kb = 0; kb < 4; kb++)
#pragma unroll
      for (int j = 0; j < 4; j++) {
        float pv = exp2_hw(sc[kb][j] - mnew);
        sc[kb][j] = pv;
        sum += pv;
      }
    sum += __shfl_xor(sum, 16);
    sum += __shfl_xor(sum, 32);
    if (grow) {
      const float es = exp2_hw(m_r - mnew);
      l_r = l_r * es + sum;
      m_r = mnew;
#pragma unroll
      for (int nb = 0; nb < 4; nb++)
#pragma unroll
        for (int j = 0; j < 4; j++) acc[nb][j] *= es;   // acc q=c == es lane
    } else {
      l_r += sum;
    }

    // ---- P^T -> B-frags via wave-private swizzled LDS ---------------------
    // write: key-dword kdw = 8kb+2g+w at Pw[c*32 + (kdw ^ cx)]
#pragma unroll
    for (int kb = 0; kb < 4; kb++) {
      u32x2 pr;
      pr.x = cvtpk_bf16(sc[kb][0], sc[kb][1]);
      pr.y = cvtpk_bf16(sc[kb][2], sc[kb][3]);
      *(u32x2*)(Pw + c * 32 + ((8 * kb + 2 * g) ^ cx)) = pr;
    }
    // read: B-frag kk = keys 32kk+8g..+7 = kdw 16kk+4g..+3 (same XOR)
#pragma unroll
    for (int kk = 0; kk < 2; kk++) {
      u32x4 pdw = *(const u32x4*)(Pw + c * 32 + ((16 * kk + 4 * g) ^ cx));
      short8 pb = __builtin_bit_cast(short8, pdw);
#pragma unroll
      for (int nb = 0; nb < 4; nb++) {
        int row = nb * 16 + c;
        short8 va = *(const short8*)(Vs + row * 64 + ((kk * 4 + g) ^ (c & 7)) * 8);
        acc[nb] = MFMA(va, pb, acc[nb]);   // A=V^T, B=P^T -> O^T
      }
    }
    __syncthreads();
  }

  // ---- epilogue: lane (c,g) holds O[q=c][d=16nb+4g+j] ----------------------
  const float inv = 1.f / l_r;
  const size_t orow = (baseBS + q0 + c) * DD + h * 64;
#pragma unroll
  for (int nb = 0; nb < 4; nb++) {
    us4 o;
#pragma unroll
    for (int j = 0; j < 4; j++) o[j] = f2bf(acc[nb][j] * inv);
    *(us4*)(AO + orow + nb * 16 + 4 * g) = o;
  }
}

extern "C" void kernel_launch(void* const* d_in, const int* in_sizes, int n_in,
                              void* d_out, int out_size, void* d_ws, size_t ws_size,
                              hipStream_t stream) {
  const float* enc = (const float*)d_in[0];
  const int* padMask = (const int*)d_in[1];
  const float* Wq = (const float*)d_in[2];
  const float* bq = (const float*)d_in[3];
  const float* Wk = (const float*)d_in[4];
  const float* bk = (const float*)d_in[5];
  const float* Wv = (const float*)d_in[6];
  const float* bv = (const float*)d_in[7];
  const float* Wo = (const float*)d_in[8];
  const float* bo = (const float*)d_in[9];
  float* out = (float*)d_out;

  const size_t NTOK = (size_t)MM;          // 8192 rows
  unsigned short* Qb = (unsigned short*)d_ws;
  unsigned short* Kb = Qb + NTOK * DD;
  unsigned short* Vb = Kb + NTOK * DD;
  unsigned short* Vt = Vb + NTOK * DD;
  unsigned short* AO = Vb;                 // alias: Vb dead after transpose
  unsigned short* Ebf = Vt + NTOK * DD;
  unsigned short* Wqb = Ebf + NTOK * DD;   // Wqb,Wkb,Wvb contiguous
  unsigned short* Wkb = Wqb + (size_t)DD * DD;
  unsigned short* Wvb = Wkb + (size_t)DD * DD;
  unsigned short* Wob = Wvb + (size_t)DD * DD;

  const size_t need_ext =
      (5 * NTOK * DD + 4 * (size_t)DD * DD) * sizeof(unsigned short);
  const bool ext = ws_size >= need_ext;    // fixed per deployment

  const float QSC = LOG2E / 64.f;          // 1/64 and log2e folded into Q
  dim3 blk(256);
  dim3 gT(SS / 64, 4 * 16);                // (32, 64)

  if (ext) {
    const int n8e = (int)(NTOK * DD / 8);  // 1048576
    const int n8w = DD * DD / 8;           // 131072
    cvt_f32_bf16<<<n8e / 256, blk, 0, stream>>>(enc, Ebf, n8e);
    cvt_w4<<<dim3(n8w / 256, 4), blk, 0, stream>>>(Wq, Wk, Wv, Wo,
                                                   Wqb, Wkb, Wvb, Wob);
    gemm_swz<3, 1><<<1536, blk, 0, stream>>>(Ebf, Wqb, bq, bk, bv, (void*)Qb,
                                             QSC, 1.f, 1.f);
    transpose_v<<<gT, blk, 0, stream>>>(Vb, Vt);
    attn_kernel<<<gT, blk, 0, stream>>>(Qb, Kb, Vt, padMask, AO);
    gemm_swz<1, 0><<<512, blk, 0, stream>>>(AO, Wob, bo, bo, bo, (void*)out,
                                            1.f, 1.f, 1.f);
  } else {
    dim3 gGemm(DD / 128, NTOK / 128);      // (8, 64)
    gemm_bt<0, 1><<<gGemm, blk, 0, stream>>>(enc, Wq, bq, (void*)Qb, QSC);
    gemm_bt<0, 1><<<gGemm, blk, 0, stream>>>(enc, Wk, bk, (void*)Kb, 1.f);
    gemm_bt<0, 1><<<gGemm, blk, 0, stream>>>(enc, Wv, bv, (void*)Vb, 1.f);
    transpose_v<<<gT, blk, 0, stream>>>(Vb, Vt);
    attn_kernel<<<gT, blk, 0, stream>>>(Qb, Kb, Vt, padMask, AO);
    gemm_bt<1, 0><<<gGemm, blk, 0, stream>>>(AO, Wo, bo, (void*)out, 1.f);
  }
}